// Round 9
// baseline (391.702 us; speedup 1.0000x reference)
//
#include <hip/hip_runtime.h>
#include <hip/hip_bf16.h>
#include <cstdint>
#include <cstdio>

typedef unsigned short u16;
typedef unsigned int   u32;
typedef __attribute__((ext_vector_type(8))) short bf16x8;   // 8 bf16 (4 VGPRs)
typedef __attribute__((ext_vector_type(4))) float f32x4;
typedef __attribute__((ext_vector_type(4))) u16   u16x4;
typedef __attribute__((ext_vector_type(8))) u16   u16x8;

#define GLOBAL_AS __attribute__((address_space(1)))
#define LDS_AS    __attribute__((address_space(3)))

static __device__ __forceinline__ u16 f2bf(float f) {
  u32 u = __builtin_bit_cast(u32, f);
  u = (u + 0x7fffu + ((u >> 16) & 1u)) >> 16;   // RNE
  return (u16)u;
}
static __device__ __forceinline__ float bf2f(u16 v) {
  return __builtin_bit_cast(float, (u32)v << 16);
}
static __device__ __forceinline__ void gload_lds16(const void* g, void* l) {
  __builtin_amdgcn_global_load_lds((GLOBAL_AS u32*)g, (LDS_AS u32*)l, 16, 0, 0);
}

// ---------------------------------------------------------------------------
__global__ void k_cvt(const float* __restrict__ src, int ld, int c0,
                      int rows_src, int cols4, int total4,
                      u16* __restrict__ dst, int ldd, int dcol) {
  int gid = blockIdx.x * 256 + threadIdx.x;
  if (gid >= total4) return;
  int r = gid / cols4;
  int c = (gid - r * cols4) * 4;
  u16x4 o = {0, 0, 0, 0};
  if (r < rows_src) {
    const float4 v = *(const float4*)&src[(size_t)r * ld + c0 + c];
    o[0] = f2bf(v.x); o[1] = f2bf(v.y); o[2] = f2bf(v.z); o[3] = f2bf(v.w);
  }
  *(u16x4*)&dst[(size_t)r * ldd + dcol + c] = o;
}

// ---------------------------------------------------------------------------
__global__ void k_init(const float* __restrict__ rough,
                       const float* __restrict__ bout,
                       float* __restrict__ out) {
  int i = blockIdx.x * 256 + threadIdx.x;
  if (i >= 1024 * 65) return;
  int bi = i / 65, c = i - bi * 65;
  out[i] = (c == 0) ? 1e-7f : rough[bi * 64 + c - 1] + bout[0];
}

// ---------------------------------------------------------------------------
// counting sort of 65536 pairs by mention index (10000 buckets, padded 10240)
__global__ void k_hist(const int* __restrict__ tidx, int* __restrict__ cnt) {
  int i = blockIdx.x * 256 + threadIdx.x;   // grid 256x256 = 65536 exact
  atomicAdd(&cnt[tidx[i]], 1);
}

__global__ void k_scan(int* __restrict__ cnt) {   // 1 block, 512 thr, 20/thr
  __shared__ int part[512];
  int t = threadIdx.x;
  int local[20], s = 0;
#pragma unroll
  for (int i = 0; i < 20; ++i) { local[i] = cnt[t * 20 + i]; s += local[i]; }
  part[t] = s;
  __syncthreads();
  for (int off = 1; off < 512; off <<= 1) {
    int v = (t >= off) ? part[t - off] : 0;
    __syncthreads();
    part[t] += v;
    __syncthreads();
  }
  int ex = part[t] - s;                     // exclusive prefix of this chunk
#pragma unroll
  for (int i = 0; i < 20; ++i) { int c = local[i]; cnt[t * 20 + i] = ex; ex += c; }
}

__global__ void k_scatter(const int* __restrict__ tidx, int* __restrict__ cnt,
                          int* __restrict__ perm, int* __restrict__ miS) {
  int i = blockIdx.x * 256 + threadIdx.x;   // 65536 exact
  int mi = tidx[i];
  int pos = atomicAdd(&cnt[mi], 1);
  perm[pos] = i;
  miS[pos] = mi;
}

// ---------------------------------------------------------------------------
// gemm128: 128x128 2-phase kernel, used only for the tiny Aproj GEMM.
__global__ __launch_bounds__(256)
void gemm128(const u16* __restrict__ A, int lda,
             const u16* __restrict__ B, int ldb, int Ksteps,
             u16* __restrict__ C, int ldc, const float* __restrict__ bias) {
  __shared__ u16 As[128 * 64];
  __shared__ u16 Bs[128 * 64];
  const int t = threadIdx.x;
  const int w = t >> 6, l = t & 63;
  const int wr = w >> 1, wc = w & 1;
  const int brow = blockIdx.x * 128;
  const int bcol = blockIdx.y * 128;
  const int srow = t >> 3;
  const int scol = (t & 7) * 8;
  const int gsw  = (((t & 7) ^ ((t >> 3) & 7))) * 8;

  f32x4 acc[4][4] = {};
  for (int ks = 0; ks < Ksteps; ++ks) {
    const int kb = ks * 64;
#pragma unroll
    for (int q = 0; q < 4; ++q) {
      int r = q * 32 + srow;
      gload_lds16(A + (size_t)(brow + r) * lda + kb + gsw, &As[r * 64 + scol]);
      gload_lds16(B + (size_t)(bcol + r) * ldb + kb + gsw, &Bs[r * 64 + scol]);
    }
    __syncthreads();
#pragma unroll
    for (int kk = 0; kk < 2; ++kk) {
      bf16x8 af[4], bfr[4];
      const int pg = ((kk * 4 + (l >> 4)) ^ (l & 7)) * 8;
#pragma unroll
      for (int m = 0; m < 4; ++m)
        af[m] = *(const bf16x8*)&As[(wr * 64 + m * 16 + (l & 15)) * 64 + pg];
#pragma unroll
      for (int n = 0; n < 4; ++n)
        bfr[n] = *(const bf16x8*)&Bs[(wc * 64 + n * 16 + (l & 15)) * 64 + pg];
#pragma unroll
      for (int m = 0; m < 4; ++m)
#pragma unroll
        for (int n = 0; n < 4; ++n)
          acc[m][n] = __builtin_amdgcn_mfma_f32_16x16x32_bf16(af[m], bfr[n], acc[m][n], 0, 0, 0);
    }
    __syncthreads();
  }
#pragma unroll
  for (int m = 0; m < 4; ++m)
#pragma unroll
    for (int n = 0; n < 4; ++n)
#pragma unroll
      for (int reg = 0; reg < 4; ++reg) {
        int row = brow + wr * 64 + m * 16 + (l >> 4) * 4 + reg;
        int col = bcol + wc * 64 + n * 16 + (l & 15);
        float v = acc[m][n][reg] + (bias ? bias[col] : 0.f);
        C[(size_t)row * ldc + col] = f2bf(v);
      }
}

// ---------------------------------------------------------------------------
// gemm256, 256x256, BK=64, 512 thr (8 waves 2Mx4N).
// FUSED=false: r5 schedule verbatim (Aproj/Bproj GEMM).
// FUSED=true (sorted pairs, in-LDS build):
//   LDS: As[2buf][2half][128][64] (raw allm16[mi] -> product), Ms[2half][128][64]
//   single-buffered (a16[bi] multiplier rows), Bs[256][64] single-buffered.
//   All staging via gload_lds -> everything lives in ONE counted FIFO ledger:
//     q0: issue M/A(t+1,h0) [4]
//     q1: issue B(t+1) [4] then M/A(t+1,h1) [4]   (B older -> cheaper wait)
//     q0-post: vmcnt(4) lands M/A(t,h1) [3-phase distance]; RMW(t,h1)
//     q3-post: vmcnt(4) lands B(t+1)+M/A(t+1,h0) [3-phase]; RMW(t+1,h0)
//   Tail counts 2/0 at NT-2/NT-1 (stages skipped there; pwb tile needs no
//   multiply). Single-buffer discipline: every stage/RMW target is >=1
//   barrier after its last reader.
template<bool FUSED>
__global__ __launch_bounds__(512, 1)
void gemm256(const u16* __restrict__ A, int lda,
             const u16* __restrict__ B, int ldb, int NT,
             u16* __restrict__ C, int ldc,
             const u16* __restrict__ a16, const u16* __restrict__ allm16,
             const u16* __restrict__ pwb,
             const u16* __restrict__ Aproj, const u16* __restrict__ Bproj,
             const float* __restrict__ Wout,
             const int* __restrict__ perm, const int* __restrict__ miS,
             float* __restrict__ out) {
  extern __shared__ u16 lds[];
  u16* As = lds;                        // [2][2][128][64], rows bit5-interleaved
  u16* Bs = lds + 2 * 2 * 128 * 64;     // false: [2][256][64]; true: [256][64]
  u16* Ms = Bs + 256 * 64;              // true only: [2][128][64]

  const int t = threadIdx.x;
  const int l = t & 63;
  const int w = t >> 6;                 // 0..7
  const int wrow = w >> 2, wcol = w & 3;
  const int brow = blockIdx.x * 256;
  const int bcol = blockIdx.y * 256;

  const int sr  = t >> 3;               // 0..63
  const int sc  = (t & 7) * 8;          // linear LDS dest col
  const int gsw = ((t & 7) ^ (sr & 7)) * 8;  // pre-swizzled source col

  int mi_[2][2], pair_[2][2];
  if constexpr (FUSED) {
#pragma unroll
    for (int h = 0; h < 2; ++h)
#pragma unroll
      for (int s = 0; s < 2; ++s) {
        int lr = sr + 64 * s;
        int g  = ((lr >> 5) << 6) + h * 32 + (lr & 31);
        pair_[h][s] = perm[brow + g];
        mi_[h][s]   = miS[brow + g];
      }
  }

  f32x4 acc[8][4] = {};

  if constexpr (FUSED) {
    // ---------------- fused path ----------------
    auto stageRawA = [&](int kt, int h) {   // raw b rows (or pwb) -> As
      if (kt >= NT) return;
#pragma unroll
      for (int s = 0; s < 2; ++s) {
        int lr = sr + 64 * s;
        const u16* src = (kt == NT - 1)
            ? (pwb + (size_t)pair_[h][s] * 64 + gsw)
            : (allm16 + (size_t)mi_[h][s] * 1024 + kt * 64 + gsw);
        gload_lds16(src, &As[(((kt & 1) * 2 + h) * 128 + lr) * 64 + sc]);
      }
    };
    auto stageM = [&](int kt, int h) {      // a16[bi] multiplier rows -> Ms
      if (kt >= NT - 1) return;             // pw tile: no multiplier
#pragma unroll
      for (int s = 0; s < 2; ++s) {
        int lr = sr + 64 * s;
        gload_lds16(a16 + (size_t)(pair_[h][s] >> 6) * 1024 + kt * 64 + gsw,
                    &Ms[(h * 128 + lr) * 64 + sc]);
      }
    };
    auto stageBt = [&](int kt, int h) {     // single-buffered B
      if (kt >= NT) return;
#pragma unroll
      for (int s = 0; s < 2; ++s) {
        int lr = h * 128 + sr + 64 * s;
        gload_lds16(B + (size_t)(bcol + lr) * ldb + kt * 64 + gsw,
                    &Bs[lr * 64 + sc]);
      }
    };
    auto rmwFin = [&](int kt1, int h) {     // raw -> product in place
      if (kt1 >= NT - 1) return;
      const int cb = kt1 & 1;
#pragma unroll
      for (int s = 0; s < 2; ++s) {
        int lr = sr + 64 * s;
        u16x8 b = *(const u16x8*)&As[((cb * 2 + h) * 128 + lr) * 64 + sc];
        u16x8 a = *(const u16x8*)&Ms[(h * 128 + lr) * 64 + sc];
        u16x8 o;
#pragma unroll
        for (int j = 0; j < 8; ++j) o[j] = f2bf(bf2f(a[j]) * bf2f(b[j]));
        *(u16x8*)&As[((cb * 2 + h) * 128 + lr) * 64 + sc] = o;
      }
    };

    // prologue: 12 loads; vmcnt(8) lands M/A(0,h0); rmw; vmcnt(4) lands B(0).
    stageM(0, 0); stageRawA(0, 0);
    stageBt(0, 0); stageBt(0, 1);
    stageM(0, 1); stageRawA(0, 1);
    asm volatile("s_waitcnt vmcnt(8)" ::: "memory");
    rmwFin(0, 0);
    asm volatile("s_waitcnt lgkmcnt(0)" ::: "memory");
    asm volatile("s_waitcnt vmcnt(4)" ::: "memory");
    __builtin_amdgcn_s_barrier();

    for (int kt = 0; kt < NT; ++kt) {
      const int cbuf = kt & 1;
      bf16x8 bfr[4][2];
#pragma unroll
      for (int q = 0; q < 4; ++q) {
        // --- ds reads (pre-barrier) ---
        if (q == 0) {
#pragma unroll
          for (int n = 0; n < 4; ++n) {
            int row = wcol * 64 + n * 16 + (l & 15);
#pragma unroll
            for (int kk = 0; kk < 2; ++kk) {
              int gran = (kk * 4 + (l >> 4)) ^ (l & 7);
              bfr[n][kk] = *(const bf16x8*)&Bs[row * 64 + gran * 8];
            }
          }
        }
        bf16x8 af[2][2];
#pragma unroll
        for (int m2 = 0; m2 < 2; ++m2) {
          int m = 2 * q + m2;
          int g = wrow * 128 + m * 16 + (l & 15);
          int lra = ((g >> 6) << 5) + (g & 31);
#pragma unroll
          for (int kk = 0; kk < 2; ++kk) {
            int gran = (kk * 4 + (l >> 4)) ^ (l & 7);
            af[m2][kk] = *(const bf16x8*)&As[((cbuf * 2 + (q & 1)) * 128 + lra) * 64 + gran * 8];
          }
        }

        // --- staging ---
        if (q == 0) {
          stageM(kt + 1, 0); stageRawA(kt + 1, 0);
        } else if (q == 1) {
          stageBt(kt + 1, 0); stageBt(kt + 1, 1);    // B first (older)
          stageM(kt + 1, 1); stageRawA(kt + 1, 1);
        }

        if (q == 0) asm volatile("s_waitcnt lgkmcnt(8)" ::: "memory");
        __builtin_amdgcn_s_barrier();
        asm volatile("s_waitcnt lgkmcnt(0)" ::: "memory");
        __builtin_amdgcn_sched_barrier(0);
        __builtin_amdgcn_s_setprio(1);
#pragma unroll
        for (int m2 = 0; m2 < 2; ++m2)
#pragma unroll
          for (int n = 0; n < 4; ++n)
#pragma unroll
            for (int kk = 0; kk < 2; ++kk)
              acc[2 * q + m2][n] = __builtin_amdgcn_mfma_f32_16x16x32_bf16(
                  af[m2][kk], bfr[n][kk], acc[2 * q + m2][n], 0, 0, 0);
        __builtin_amdgcn_s_setprio(0);

        // --- counted waits + RMW, then closing barrier ---
        if (q == 0) {
          if (kt < NT - 2)       asm volatile("s_waitcnt vmcnt(4)" ::: "memory");
          else if (kt == NT - 2) asm volatile("s_waitcnt vmcnt(2)" ::: "memory");
          else                   asm volatile("s_waitcnt vmcnt(0)" ::: "memory");
          rmwFin(kt, 1);
          asm volatile("s_waitcnt lgkmcnt(0)" ::: "memory");
        } else if (q == 3 && kt + 1 < NT) {
          if (kt < NT - 2) asm volatile("s_waitcnt vmcnt(4)" ::: "memory");
          else             asm volatile("s_waitcnt vmcnt(2)" ::: "memory");
          rmwFin(kt + 1, 0);
          asm volatile("s_waitcnt lgkmcnt(0)" ::: "memory");
        }
        __builtin_amdgcn_s_barrier();
      }
    }
  } else {
    // ---------------- plain path (r5 ledger, verbatim) ----------------
    auto stageA = [&](int kt, int h) {
      if (kt >= NT) return;
#pragma unroll
      for (int s = 0; s < 2; ++s) {
        int lr = sr + 64 * s;
        int g  = ((lr >> 5) << 6) + h * 32 + (lr & 31);
        gload_lds16(A + (size_t)(brow + g) * lda + kt * 64 + gsw,
                    &As[(((kt & 1) * 2 + h) * 128 + lr) * 64 + sc]);
      }
    };
    auto stageB2 = [&](int kt, int h) {
      if (kt >= NT) return;
#pragma unroll
      for (int s = 0; s < 2; ++s) {
        int lr = h * 128 + sr + 64 * s;
        gload_lds16(B + (size_t)(bcol + lr) * ldb + kt * 64 + gsw,
                    &Bs[((kt & 1) * 256 + lr) * 64 + sc]);
      }
    };

    stageB2(0, 0); stageB2(0, 1); stageA(0, 0); stageA(0, 1);
    stageB2(1, 0); stageB2(1, 1);
    asm volatile("s_waitcnt vmcnt(6)" ::: "memory");
    __builtin_amdgcn_s_barrier();

    for (int kt = 0; kt < NT; ++kt) {
      const int cbuf = kt & 1;
      bf16x8 bfr[4][2];
#pragma unroll
      for (int q = 0; q < 4; ++q) {
        if (q == 0) {
#pragma unroll
          for (int n = 0; n < 4; ++n) {
            int row = wcol * 64 + n * 16 + (l & 15);
#pragma unroll
            for (int kk = 0; kk < 2; ++kk) {
              int gran = (kk * 4 + (l >> 4)) ^ (l & 7);
              bfr[n][kk] = *(const bf16x8*)&Bs[(cbuf * 256 + row) * 64 + gran * 8];
            }
          }
        }
        bf16x8 af[2][2];
#pragma unroll
        for (int m2 = 0; m2 < 2; ++m2) {
          int m = 2 * q + m2;
          int g = wrow * 128 + m * 16 + (l & 15);
          int lra = ((g >> 6) << 5) + (g & 31);
#pragma unroll
          for (int kk = 0; kk < 2; ++kk) {
            int gran = (kk * 4 + (l >> 4)) ^ (l & 7);
            af[m2][kk] = *(const bf16x8*)&As[((cbuf * 2 + (q & 1)) * 128 + lra) * 64 + gran * 8];
          }
        }

        if      (q == 0) stageA(kt + 1, 0);
        else if (q == 1) stageA(kt + 1, 1);
        else if (q == 2) stageB2(kt + 2, 0);
        else             stageB2(kt + 2, 1);

        if (q == 0) asm volatile("s_waitcnt lgkmcnt(8)" ::: "memory");
        __builtin_amdgcn_s_barrier();
        asm volatile("s_waitcnt lgkmcnt(0)" ::: "memory");
        __builtin_amdgcn_sched_barrier(0);
        __builtin_amdgcn_s_setprio(1);
#pragma unroll
        for (int m2 = 0; m2 < 2; ++m2)
#pragma unroll
          for (int n = 0; n < 4; ++n)
#pragma unroll
            for (int kk = 0; kk < 2; ++kk)
              acc[2 * q + m2][n] = __builtin_amdgcn_mfma_f32_16x16x32_bf16(
                  af[m2][kk], bfr[n][kk], acc[2 * q + m2][n], 0, 0, 0);
        __builtin_amdgcn_s_setprio(0);

        if (q == 0) {
          if (kt + 1 < NT) asm volatile("s_waitcnt vmcnt(6)" ::: "memory");
          else             asm volatile("s_waitcnt vmcnt(0)" ::: "memory");
        } else if (q == 3 && kt + 1 < NT) {
          if (kt + 2 < NT) asm volatile("s_waitcnt vmcnt(6)" ::: "memory");
          else             asm volatile("s_waitcnt vmcnt(2)" ::: "memory");
        }
        __builtin_amdgcn_s_barrier();
      }
    }
  }

  // --- epilogue ---
  if constexpr (FUSED) {
    __syncthreads();
    u16* Pb = lds;                      // [256][256], src+read XOR key=((row>>1)&7)
#pragma unroll
    for (int pass = 0; pass < 16; ++pass) {
      int rr = pass * 16 + (t >> 5);
      int mi = miS[brow + rr];
      int cc = (t & 31) * 8;
      int scc = cc ^ (((rr >> 1) & 7) << 3);
      gload_lds16(&Bproj[(size_t)mi * 1024 + bcol + scc], &Pb[rr * 256 + cc]);
    }
    asm volatile("s_waitcnt vmcnt(0)" ::: "memory");
    __syncthreads();

    float wo[4];
#pragma unroll
    for (int n = 0; n < 4; ++n)
      wo[n] = Wout[bcol + wcol * 64 + n * 16 + (l & 15)];
#pragma unroll
    for (int m = 0; m < 8; ++m) {
#pragma unroll
      for (int reg = 0; reg < 4; ++reg) {
        int lrow = wrow * 128 + m * 16 + (l >> 4) * 4 + reg;
        int pr = perm[brow + lrow];
        int bi = pr >> 6;
        int key = ((lrow >> 1) & 7) << 3;
        float s = 0.f;
#pragma unroll
        for (int n = 0; n < 4; ++n) {
          int lcol = wcol * 64 + n * 16 + (l & 15);
          float v = acc[m][n][reg] + bf2f(Aproj[(size_t)bi * 1024 + bcol + lcol])
                  + bf2f(Pb[lrow * 256 + (lcol ^ key)]);
          v = v > 0.f ? v : 0.01f * v;          // leaky_relu(0.01)
          s += v * wo[n];
        }
        s += __shfl_xor(s, 1);
        s += __shfl_xor(s, 2);
        s += __shfl_xor(s, 4);
        s += __shfl_xor(s, 8);
        if ((l & 15) == 0)
          atomicAdd(&out[bi * 65 + 1 + (pr & 63)], s);
      }
    }
  } else {
#pragma unroll
    for (int m = 0; m < 8; ++m)
#pragma unroll
      for (int n = 0; n < 4; ++n)
#pragma unroll
        for (int reg = 0; reg < 4; ++reg) {
          int row = brow + wrow * 128 + m * 16 + (l >> 4) * 4 + reg;
          int col = bcol + wcol * 64 + n * 16 + (l & 15);
          C[(size_t)row * ldc + col] = f2bf(acc[m][n][reg]);
        }
  }
}

// ---------------------------------------------------------------------------
extern "C" void kernel_launch(void* const* d_in, const int* in_sizes, int n_in,
                              void* d_out, int out_size, void* d_ws, size_t ws_size,
                              hipStream_t stream) {
  const float* allm  = (const float*)d_in[0];   // [10000,1024]
  const float* ments = (const float*)d_in[1];   // [1024,1024]
  const float* pw    = (const float*)d_in[2];   // [1024,64,64]
  const int*   tidx  = (const int*)d_in[3];     // [1024,64]
  const float* rough = (const float*)d_in[4];   // [1024,64]
  const float* W1    = (const float*)d_in[5];   // [1024,3136]
  const float* b1    = (const float*)d_in[6];   // [1024]
  const float* Wout  = (const float*)d_in[7];   // [1,1024]
  const float* bout  = (const float*)d_in[8];   // [1]
  float* out = (float*)d_out;                   // [1024,65]

  u16* A16    = (u16*)d_ws;                 // 1024*1024 (ments bf16)
  u16* allm16 = A16 + 1024 * 1024;          // 10240*1024 (rows>=10000 zero)
  u16* W1a    = allm16 + 10240 * 1024;      // 1024*1024
  u16* W1b    = W1a + 1024 * 1024;          // 1024*1024
  u16* W1cp   = W1b + 1024 * 1024;          // 1024*1088
  u16* Aproj  = W1cp + 1024 * 1088;         // 1024*1024 bf16 (holds Aproj+b1)
  u16* Bproj  = Aproj + 1024 * 1024;        // 10240*1024 bf16
  u16* pwb    = Bproj + 10240 * 1024;       // 65536*64 bf16 (pw)
  int* cnt    = (int*)(pwb + (size_t)65536 * 64);  // 10240
  int* perm   = cnt + 10240;                // 65536
  int* miS    = perm + 65536;               // 65536

  size_t need = (size_t)2 * ((size_t)1024*1024 + 10240*1024 + 1024*1024 + 1024*1024
              + 1024*1088 + 1024*1024 + 10240*1024 + (size_t)65536*64)
              + (size_t)4 * (10240 + 65536 + 65536);
  if (ws_size < need) {
    fprintf(stderr, "kernel_launch: ws_size %zu < needed %zu\n", ws_size, need);
    return;
  }

  hipFuncSetAttribute((const void*)&gemm256<false>,
                      hipFuncAttributeMaxDynamicSharedMemorySize, 131072);
  hipFuncSetAttribute((const void*)&gemm256<true>,
                      hipFuncAttributeMaxDynamicSharedMemorySize, 131072);

  // --- counting sort of pairs by mention index ---
  hipMemsetAsync(cnt, 0, 10240 * sizeof(int), stream);
  k_hist<<<256, 256, 0, stream>>>(tidx, cnt);
  k_scan<<<1, 512, 0, stream>>>(cnt);
  k_scatter<<<256, 256, 0, stream>>>(tidx, cnt, perm, miS);

  // --- conversions / weight splits (bf16) ---
  {
    int t4;
    t4 = 1024 * 256;
    k_cvt<<<(t4 + 255) / 256, 256, 0, stream>>>(W1, 3136, 0,    1024, 256, t4, W1a, 1024, 0);
    k_cvt<<<(t4 + 255) / 256, 256, 0, stream>>>(W1, 3136, 1024, 1024, 256, t4, W1b, 1024, 0);
    k_cvt<<<(t4 + 255) / 256, 256, 0, stream>>>(W1, 3136, 2048, 1024, 256, t4, W1cp, 1088, 0);
    t4 = 1024 * 16;
    k_cvt<<<(t4 + 255) / 256, 256, 0, stream>>>(W1, 3136, 3072, 1024, 16, t4, W1cp, 1088, 1024);
    t4 = 1024 * 256;
    k_cvt<<<(t4 + 255) / 256, 256, 0, stream>>>(ments, 1024, 0, 1024, 256, t4, A16, 1024, 0);
    t4 = 10240 * 256;
    k_cvt<<<(t4 + 255) / 256, 256, 0, stream>>>(allm, 1024, 0, 10000, 256, t4, allm16, 1024, 0);
    t4 = 65536 * 16;                           // pw -> bf16 (pwb), row = pair
    k_cvt<<<(t4 + 255) / 256, 256, 0, stream>>>(pw, 64, 0, 65536, 16, t4, pwb, 64, 0);
  }

  // --- projection GEMMs (Aproj gets +b1 folded) ---
  gemm128<<<dim3(8, 8), 256, 0, stream>>>(A16, 1024, W1a, 1024, 16, Aproj, 1024, b1);
  gemm256<false><<<dim3(40, 4), 512, 131072, stream>>>(allm16, 1024, W1b, 1024, 16,
                                                       Bproj, 1024,
                                                       nullptr, nullptr, nullptr,
                                                       nullptr, nullptr, nullptr,
                                                       nullptr, nullptr, nullptr);

  // --- init out with EPS column and rough+bout ---
  k_init<<<260, 256, 0, stream>>>(rough, bout, out);

  // --- single fused dispatch over sorted pairs ---
  gemm256<true><<<dim3(256, 4), 512, 131072, stream>>>(nullptr, 0, W1cp, 1088, 17,
                                                       nullptr, 0,
                                                       A16, allm16, pwb,
                                                       Aproj, Bproj, Wout,
                                                       perm, miS, out);
}

// Round 10
// 388.614 us; speedup vs baseline: 1.0079x; 1.0079x over previous
//
#include <hip/hip_runtime.h>
#include <hip/hip_bf16.h>
#include <cstdint>
#include <cstdio>

typedef unsigned short u16;
typedef unsigned int   u32;
typedef __attribute__((ext_vector_type(8))) short bf16x8;   // 8 bf16 (4 VGPRs)
typedef __attribute__((ext_vector_type(4))) float f32x4;
typedef __attribute__((ext_vector_type(4))) u16   u16x4;
typedef __attribute__((ext_vector_type(8))) u16   u16x8;

#define GLOBAL_AS __attribute__((address_space(1)))
#define LDS_AS    __attribute__((address_space(3)))

static __device__ __forceinline__ u16 f2bf(float f) {
  u32 u = __builtin_bit_cast(u32, f);
  u = (u + 0x7fffu + ((u >> 16) & 1u)) >> 16;   // RNE
  return (u16)u;
}
static __device__ __forceinline__ float bf2f(u16 v) {
  return __builtin_bit_cast(float, (u32)v << 16);
}
static __device__ __forceinline__ void gload_lds16(const void* g, void* l) {
  __builtin_amdgcn_global_load_lds((GLOBAL_AS u32*)g, (LDS_AS u32*)l, 16, 0, 0);
}

// ---------------------------------------------------------------------------
__global__ void k_cvt(const float* __restrict__ src, int ld, int c0,
                      int rows_src, int cols4, int total4,
                      u16* __restrict__ dst, int ldd, int dcol) {
  int gid = blockIdx.x * 256 + threadIdx.x;
  if (gid >= total4) return;
  int r = gid / cols4;
  int c = (gid - r * cols4) * 4;
  u16x4 o = {0, 0, 0, 0};
  if (r < rows_src) {
    const float4 v = *(const float4*)&src[(size_t)r * ld + c0 + c];
    o[0] = f2bf(v.x); o[1] = f2bf(v.y); o[2] = f2bf(v.z); o[3] = f2bf(v.w);
  }
  *(u16x4*)&dst[(size_t)r * ldd + dcol + c] = o;
}

// ---------------------------------------------------------------------------
__global__ void k_init(const float* __restrict__ rough,
                       const float* __restrict__ bout,
                       float* __restrict__ out) {
  int i = blockIdx.x * 256 + threadIdx.x;
  if (i >= 1024 * 65) return;
  int bi = i / 65, c = i - bi * 65;
  out[i] = (c == 0) ? 1e-7f : rough[bi * 64 + c - 1] + bout[0];
}

// ---------------------------------------------------------------------------
// k_build_cmat: bf16 sources, 8 elems/thread. 136 = 1088/8 groups per row.
__global__ void k_build_cmat(const u16* __restrict__ A16,
                             const u16* __restrict__ allm16,
                             const float* __restrict__ pw,
                             const int* __restrict__ topidx,
                             u16* __restrict__ Cmat, int r0) {
  int gid = blockIdx.x * 256 + threadIdx.x;   // 16384*136 exact
  int lr = gid / 136;
  int c8 = gid - lr * 136;
  int r  = r0 + lr;
  u16x8 o;
  if (c8 < 128) {
    int k   = c8 * 8;
    int idx = topidx[r];
    int bi  = r >> 6;
    u16x8 a = *(const u16x8*)&A16[(size_t)bi * 1024 + k];
    u16x8 b = *(const u16x8*)&allm16[(size_t)idx * 1024 + k];
#pragma unroll
    for (int j = 0; j < 8; ++j) o[j] = f2bf(bf2f(a[j]) * bf2f(b[j]));
  } else {
    int k = (c8 - 128) * 8;
    float4 p0 = *(const float4*)&pw[(size_t)r * 64 + k];
    float4 p1 = *(const float4*)&pw[(size_t)r * 64 + k + 4];
    o[0] = f2bf(p0.x); o[1] = f2bf(p0.y); o[2] = f2bf(p0.z); o[3] = f2bf(p0.w);
    o[4] = f2bf(p1.x); o[5] = f2bf(p1.y); o[6] = f2bf(p1.z); o[7] = f2bf(p1.w);
  }
  *(u16x8*)&Cmat[(size_t)lr * 1088 + c8 * 8] = o;
}

// ---------------------------------------------------------------------------
// gemm128: 128x128 2-phase kernel, used only for the tiny Aproj GEMM.
__global__ __launch_bounds__(256)
void gemm128(const u16* __restrict__ A, int lda,
             const u16* __restrict__ B, int ldb, int Ksteps,
             u16* __restrict__ C, int ldc, const float* __restrict__ bias) {
  __shared__ u16 As[128 * 64];
  __shared__ u16 Bs[128 * 64];
  const int t = threadIdx.x;
  const int w = t >> 6, l = t & 63;
  const int wr = w >> 1, wc = w & 1;
  const int brow = blockIdx.x * 128;
  const int bcol = blockIdx.y * 128;
  const int srow = t >> 3;
  const int scol = (t & 7) * 8;
  const int gsw  = (((t & 7) ^ ((t >> 3) & 7))) * 8;

  f32x4 acc[4][4] = {};
  for (int ks = 0; ks < Ksteps; ++ks) {
    const int kb = ks * 64;
#pragma unroll
    for (int q = 0; q < 4; ++q) {
      int r = q * 32 + srow;
      gload_lds16(A + (size_t)(brow + r) * lda + kb + gsw, &As[r * 64 + scol]);
      gload_lds16(B + (size_t)(bcol + r) * ldb + kb + gsw, &Bs[r * 64 + scol]);
    }
    __syncthreads();
#pragma unroll
    for (int kk = 0; kk < 2; ++kk) {
      bf16x8 af[4], bfr[4];
      const int pg = ((kk * 4 + (l >> 4)) ^ (l & 7)) * 8;
#pragma unroll
      for (int m = 0; m < 4; ++m)
        af[m] = *(const bf16x8*)&As[(wr * 64 + m * 16 + (l & 15)) * 64 + pg];
#pragma unroll
      for (int n = 0; n < 4; ++n)
        bfr[n] = *(const bf16x8*)&Bs[(wc * 64 + n * 16 + (l & 15)) * 64 + pg];
#pragma unroll
      for (int m = 0; m < 4; ++m)
#pragma unroll
        for (int n = 0; n < 4; ++n)
          acc[m][n] = __builtin_amdgcn_mfma_f32_16x16x32_bf16(af[m], bfr[n], acc[m][n], 0, 0, 0);
    }
    __syncthreads();
  }
#pragma unroll
  for (int m = 0; m < 4; ++m)
#pragma unroll
    for (int n = 0; n < 4; ++n)
#pragma unroll
      for (int reg = 0; reg < 4; ++reg) {
        int row = brow + wr * 64 + m * 16 + (l >> 4) * 4 + reg;
        int col = bcol + wc * 64 + n * 16 + (l & 15);
        float v = acc[m][n][reg] + (bias ? bias[col] : 0.f);
        C[(size_t)row * ldc + col] = f2bf(v);
      }
}

// ---------------------------------------------------------------------------
// gemm256<false>: r5 schedule verbatim — Bproj GEMM only.
__global__ __launch_bounds__(512, 1)
void gemm256p(const u16* __restrict__ A, int lda,
              const u16* __restrict__ B, int ldb, int NT,
              u16* __restrict__ C, int ldc) {
  extern __shared__ u16 lds[];
  u16* As = lds;
  u16* Bs = lds + 2 * 2 * 128 * 64;

  const int t = threadIdx.x;
  const int l = t & 63;
  const int w = t >> 6;
  const int wrow = w >> 2, wcol = w & 3;
  const int brow = blockIdx.x * 256;
  const int bcol = blockIdx.y * 256;
  const int sr  = t >> 3;
  const int sc  = (t & 7) * 8;
  const int gsw = ((t & 7) ^ (sr & 7)) * 8;

  auto stageA = [&](int kt, int h) {
    if (kt >= NT) return;
#pragma unroll
    for (int s = 0; s < 2; ++s) {
      int lr = sr + 64 * s;
      int g  = ((lr >> 5) << 6) + h * 32 + (lr & 31);
      gload_lds16(A + (size_t)(brow + g) * lda + kt * 64 + gsw,
                  &As[(((kt & 1) * 2 + h) * 128 + lr) * 64 + sc]);
    }
  };
  auto stageB = [&](int kt, int h) {
    if (kt >= NT) return;
#pragma unroll
    for (int s = 0; s < 2; ++s) {
      int lr = h * 128 + sr + 64 * s;
      gload_lds16(B + (size_t)(bcol + lr) * ldb + kt * 64 + gsw,
                  &Bs[((kt & 1) * 256 + lr) * 64 + sc]);
    }
  };

  f32x4 acc[8][4] = {};
  stageB(0, 0); stageB(0, 1); stageA(0, 0); stageA(0, 1);
  stageB(1, 0); stageB(1, 1);
  asm volatile("s_waitcnt vmcnt(6)" ::: "memory");
  __builtin_amdgcn_s_barrier();

  for (int kt = 0; kt < NT; ++kt) {
    const int cbuf = kt & 1;
    bf16x8 bfr[4][2];
#pragma unroll
    for (int q = 0; q < 4; ++q) {
      if (q == 0) {
#pragma unroll
        for (int n = 0; n < 4; ++n) {
          int row = wcol * 64 + n * 16 + (l & 15);
#pragma unroll
          for (int kk = 0; kk < 2; ++kk) {
            int gran = (kk * 4 + (l >> 4)) ^ (l & 7);
            bfr[n][kk] = *(const bf16x8*)&Bs[(cbuf * 256 + row) * 64 + gran * 8];
          }
        }
      }
      bf16x8 af[2][2];
#pragma unroll
      for (int m2 = 0; m2 < 2; ++m2) {
        int m = 2 * q + m2;
        int g = wrow * 128 + m * 16 + (l & 15);
        int lra = ((g >> 6) << 5) + (g & 31);
#pragma unroll
        for (int kk = 0; kk < 2; ++kk) {
          int gran = (kk * 4 + (l >> 4)) ^ (l & 7);
          af[m2][kk] = *(const bf16x8*)&As[((cbuf * 2 + (q & 1)) * 128 + lra) * 64 + gran * 8];
        }
      }

      if      (q == 0) stageA(kt + 1, 0);
      else if (q == 1) stageA(kt + 1, 1);
      else if (q == 2) stageB(kt + 2, 0);
      else             stageB(kt + 2, 1);

      if (q == 0) asm volatile("s_waitcnt lgkmcnt(8)" ::: "memory");
      __builtin_amdgcn_s_barrier();
      asm volatile("s_waitcnt lgkmcnt(0)" ::: "memory");
      __builtin_amdgcn_sched_barrier(0);
      __builtin_amdgcn_s_setprio(1);
#pragma unroll
      for (int m2 = 0; m2 < 2; ++m2)
#pragma unroll
        for (int n = 0; n < 4; ++n)
#pragma unroll
          for (int kk = 0; kk < 2; ++kk)
            acc[2 * q + m2][n] = __builtin_amdgcn_mfma_f32_16x16x32_bf16(
                af[m2][kk], bfr[n][kk], acc[2 * q + m2][n], 0, 0, 0);
      __builtin_amdgcn_s_setprio(0);

      if (q == 0) {
        if (kt + 1 < NT) asm volatile("s_waitcnt vmcnt(6)" ::: "memory");
        else             asm volatile("s_waitcnt vmcnt(0)" ::: "memory");
      } else if (q == 3 && kt + 1 < NT) {
        if (kt + 2 < NT) asm volatile("s_waitcnt vmcnt(6)" ::: "memory");
        else             asm volatile("s_waitcnt vmcnt(2)" ::: "memory");
      }
      __builtin_amdgcn_s_barrier();
    }
  }

#pragma unroll
  for (int m = 0; m < 8; ++m)
#pragma unroll
    for (int n = 0; n < 4; ++n)
#pragma unroll
      for (int reg = 0; reg < 4; ++reg) {
        int row = brow + wrow * 128 + m * 16 + (l >> 4) * 4 + reg;
        int col = bcol + wcol * 64 + n * 16 + (l & 15);
        C[(size_t)row * ldc + col] = f2bf(acc[m][n][reg]);
      }
}

// ---------------------------------------------------------------------------
// gemm128f: fused pair GEMM. 128x128 tile, BK=64, 256 thr (4 waves 2x2),
// 8-phase, 64KB static LDS -> 2 blocks/CU (two independent barrier groups
// overlap each other's stalls; the r5 256^2 kernel had 1 block/CU lockstep).
// Per tile t (buf=t&1): phase q reads A rows {q*16..+16} u {64+q*16..+16}
// (chunks {0,2} for q0/q1, {1,3} for q2/q3); B frags register-cached at q0.
// Stages into buf^1 (fully dead): q0->B rows 0-63, q1->B 64-127,
// q2->A chunks {0,2}, q3->A chunks {1,3}. FIFO ledger (per wave, verified):
//   q1-post: vmcnt(4) lands A chunks {1,3} of tile t [needed q2/q3]
//            (t==NT-1: vmcnt(0), queue has only those 2)
//   q3-post: vmcnt(2) lands B(t+1)+A{0,2}(t+1) [needed next q0/q1]
// Epilogue: Pb[128][128] in reused LDS, XOR key ((row>>2)&3)<<4 both sides
// (32B octet separation for the 4 row-groups -> kills r5's 524K conflicts);
// Aproj(+b1) hoisted; leaky_relu; *Wout; 16-lane shfl reduce; atomicAdd.
__global__ __launch_bounds__(256, 2)
void gemm128f(const u16* __restrict__ A, int lda,
              const u16* __restrict__ B, int ldb, int NT,
              const u16* __restrict__ Aproj, const u16* __restrict__ Bproj,
              const float* __restrict__ Wout,
              const int* __restrict__ topidx, float* __restrict__ out, int r0) {
  __shared__ u16 As[2][128][64];
  __shared__ u16 Bs[2][128][64];

  const int t = threadIdx.x;
  const int l = t & 63;
  const int w = t >> 6;                 // 0..3
  const int wr = w >> 1, wc = w & 1;
  const int brow = blockIdx.x * 128;
  const int bcol = blockIdx.y * 128;

  const int sr  = t >> 3;               // 0..31
  const int sc  = (t & 7) * 8;
  const int gsw = ((t & 7) ^ (sr & 7)) * 8;   // pre-swizzled source col

  auto stageBh = [&](int kt, int h) {    // B rows h*64..h*64+63 (2 loads)
    if (kt >= NT) return;
    const int nb = kt & 1;
#pragma unroll
    for (int s = 0; s < 2; ++s) {
      int row = h * 64 + s * 32 + sr;
      gload_lds16(B + (size_t)(bcol + row) * ldb + kt * 64 + gsw,
                  &Bs[nb][row][sc]);
    }
  };
  auto stageAp = [&](int kt, int p) {    // A chunks {p, p+2} (2 loads)
    if (kt >= NT) return;
    const int nb = kt & 1;
#pragma unroll
    for (int s = 0; s < 2; ++s) {
      int row = (p + s * 2) * 32 + sr;
      gload_lds16(A + (size_t)(brow + row) * lda + kt * 64 + gsw,
                  &As[nb][row][sc]);
    }
  };

  f32x4 acc[4][4] = {};

  // prologue: tile 0 in steady-state order; need B(0)+chunks{0,2} -> vmcnt(2)
  stageBh(0, 0); stageBh(0, 1); stageAp(0, 0); stageAp(0, 1);
  asm volatile("s_waitcnt vmcnt(2)" ::: "memory");
  __builtin_amdgcn_s_barrier();

  for (int kt = 0; kt < NT; ++kt) {
    const int buf = kt & 1;
    const bool hn = (kt + 1 < NT);
    bf16x8 bfr[4][2];
#pragma unroll
    for (int q = 0; q < 4; ++q) {
      // --- ds reads (pre-barrier) ---
      if (q == 0) {
#pragma unroll
        for (int n = 0; n < 4; ++n) {
          int row = wc * 64 + n * 16 + (l & 15);
#pragma unroll
          for (int kk = 0; kk < 2; ++kk) {
            int gran = (kk * 4 + (l >> 4)) ^ (l & 7);
            bfr[n][kk] = *(const bf16x8*)&Bs[buf][row][gran * 8];
          }
        }
      }
      bf16x8 af[2];
      {
        int row = wr * 64 + q * 16 + (l & 15);
#pragma unroll
        for (int kk = 0; kk < 2; ++kk) {
          int gran = (kk * 4 + (l >> 4)) ^ (l & 7);
          af[kk] = *(const bf16x8*)&As[buf][row][gran * 8];
        }
      }

      // --- stage into dead opposite buffer ---
      if      (q == 0) stageBh(kt + 1, 0);
      else if (q == 1) stageBh(kt + 1, 1);
      else if (q == 2) stageAp(kt + 1, 0);
      else             stageAp(kt + 1, 1);

      __builtin_amdgcn_s_barrier();
      asm volatile("s_waitcnt lgkmcnt(0)" ::: "memory");
      __builtin_amdgcn_sched_barrier(0);
      __builtin_amdgcn_s_setprio(1);
#pragma unroll
      for (int n = 0; n < 4; ++n)
#pragma unroll
        for (int kk = 0; kk < 2; ++kk)
          acc[q][n] = __builtin_amdgcn_mfma_f32_16x16x32_bf16(
              af[kk], bfr[n][kk], acc[q][n], 0, 0, 0);
      __builtin_amdgcn_s_setprio(0);

      // --- counted waits (2 per tile) ---
      if (q == 1) {
        if (hn) asm volatile("s_waitcnt vmcnt(4)" ::: "memory");  // A{1,3}(kt)
        else    asm volatile("s_waitcnt vmcnt(0)" ::: "memory");
      } else if (q == 3 && hn) {
        asm volatile("s_waitcnt vmcnt(2)" ::: "memory");  // B(kt+1)+A{0,2}(kt+1)
      }
      __builtin_amdgcn_s_barrier();
    }
  }

  // --- epilogue ---
  __syncthreads();
  u16* Pb = &As[0][0][0];               // [128][128] reuse (32KB)
#pragma unroll
  for (int pass = 0; pass < 8; ++pass) {
    int rr = pass * 16 + (t >> 4);
    int mi = topidx[r0 + brow + rr];
    int cc = (t & 15) * 8;
    int scc = cc ^ (((rr >> 2) & 3) << 4);
    gload_lds16(&Bproj[(size_t)mi * 1024 + bcol + scc], &Pb[rr * 128 + cc]);
  }
  asm volatile("s_waitcnt vmcnt(0)" ::: "memory");
  __syncthreads();

  float wo[4], av[2][4];
  const int bi0 = ((r0 + brow) >> 6) + wr;   // wave rows span 1 bi per wr? rows wr*64.. -> bi = base + wr
#pragma unroll
  for (int n = 0; n < 4; ++n) {
    int col = bcol + wc * 64 + n * 16 + (l & 15);
    wo[n] = Wout[col];
    av[0][n] = bf2f(Aproj[(size_t)bi0 * 1024 + col]);        // b1 pre-folded
    av[1][n] = av[0][n];                                      // single bi per wave-row
  }
#pragma unroll
  for (int m = 0; m < 4; ++m) {
#pragma unroll
    for (int reg = 0; reg < 4; ++reg) {
      int lrow = wr * 64 + m * 16 + (l >> 4) * 4 + reg;
      int gr = r0 + brow + lrow;
      int key = ((lrow >> 2) & 3) << 4;
      float s = 0.f;
#pragma unroll
      for (int n = 0; n < 4; ++n) {
        int lcol = wc * 64 + n * 16 + (l & 15);
        float v = acc[m][n][reg] + av[0][n] + bf2f(Pb[lrow * 128 + (lcol ^ key)]);
        v = v > 0.f ? v : 0.01f * v;          // leaky_relu(0.01)
        s += v * wo[n];
      }
      s += __shfl_xor(s, 1);
      s += __shfl_xor(s, 2);
      s += __shfl_xor(s, 4);
      s += __shfl_xor(s, 8);
      if ((l & 15) == 0)
        atomicAdd(&out[(gr >> 6) * 65 + 1 + (gr & 63)], s);
    }
  }
}

// ---------------------------------------------------------------------------
extern "C" void kernel_launch(void* const* d_in, const int* in_sizes, int n_in,
                              void* d_out, int out_size, void* d_ws, size_t ws_size,
                              hipStream_t stream) {
  const float* allm  = (const float*)d_in[0];   // [10000,1024]
  const float* ments = (const float*)d_in[1];   // [1024,1024]
  const float* pw    = (const float*)d_in[2];   // [1024,64,64]
  const int*   tidx  = (const int*)d_in[3];     // [1024,64]
  const float* rough = (const float*)d_in[4];   // [1024,64]
  const float* W1    = (const float*)d_in[5];   // [1024,3136]
  const float* b1    = (const float*)d_in[6];   // [1024]
  const float* Wout  = (const float*)d_in[7];   // [1,1024]
  const float* bout  = (const float*)d_in[8];   // [1]
  float* out = (float*)d_out;                   // [1024,65]

  const int CHUNK = 16384;
  u16* A16    = (u16*)d_ws;                 // 1024*1024 (ments bf16)
  u16* allm16 = A16 + 1024 * 1024;          // 10240*1024 (rows>=10000 zero)
  u16* W1a    = allm16 + 10240 * 1024;      // 1024*1024
  u16* W1b    = W1a + 1024 * 1024;          // 1024*1024
  u16* W1cp   = W1b + 1024 * 1024;          // 1024*1088
  u16* Aproj  = W1cp + 1024 * 1088;         // 1024*1024 bf16 (holds Aproj+b1)
  u16* Bproj  = Aproj + 1024 * 1024;        // 10240*1024 bf16
  u16* Cmat   = Bproj + 10240 * 1024;       // CHUNK*1088 bf16

  size_t need = (size_t)2 * ((size_t)1024*1024 + 10240*1024 + 1024*1024 + 1024*1024
              + 1024*1088 + 1024*1024 + 10240*1024 + (size_t)CHUNK*1088);
  if (ws_size < need) {
    fprintf(stderr, "kernel_launch: ws_size %zu < needed %zu\n", ws_size, need);
    return;
  }

  hipFuncSetAttribute((const void*)&gemm256p,
                      hipFuncAttributeMaxDynamicSharedMemorySize, 131072);

  // --- conversions / weight splits (bf16) ---
  {
    int t4;
    t4 = 1024 * 256;
    k_cvt<<<(t4 + 255) / 256, 256, 0, stream>>>(W1, 3136, 0,    1024, 256, t4, W1a, 1024, 0);
    k_cvt<<<(t4 + 255) / 256, 256, 0, stream>>>(W1, 3136, 1024, 1024, 256, t4, W1b, 1024, 0);
    k_cvt<<<(t4 + 255) / 256, 256, 0, stream>>>(W1, 3136, 2048, 1024, 256, t4, W1cp, 1088, 0);
    t4 = 1024 * 16;
    k_cvt<<<(t4 + 255) / 256, 256, 0, stream>>>(W1, 3136, 3072, 1024, 16, t4, W1cp, 1088, 1024);
    t4 = 1024 * 256;
    k_cvt<<<(t4 + 255) / 256, 256, 0, stream>>>(ments, 1024, 0, 1024, 256, t4, A16, 1024, 0);
    t4 = 10240 * 256;
    k_cvt<<<(t4 + 255) / 256, 256, 0, stream>>>(allm, 1024, 0, 10000, 256, t4, allm16, 1024, 0);
  }

  // --- projection GEMMs (Aproj gets +b1 folded) ---
  gemm128<<<dim3(8, 8), 256, 0, stream>>>(A16, 1024, W1a, 1024, 16, Aproj, 1024, b1);
  gemm256p<<<dim3(40, 4), 512, 131072, stream>>>(allm16, 1024, W1b, 1024, 16, Bproj, 1024);

  // --- init out with EPS column and rough+bout ---
  k_init<<<260, 256, 0, stream>>>(rough, bout, out);

  // --- chunked: build Cmat bf16, then fused 128^2 2-resident GEMM+epilogue ---
  for (int c = 0; c < 4; ++c) {
    int r0 = c * CHUNK;
    k_build_cmat<<<(CHUNK * 136) / 256, 256, 0, stream>>>(A16, allm16, pw, tidx, Cmat, r0);
    gemm128f<<<dim3(CHUNK / 128, 8), 256, 0, stream>>>(Cmat, 1088, W1cp, 1088, 17,
                                                       Aproj, Bproj, Wout, tidx, out, r0);
  }
}

// Round 11
// 322.082 us; speedup vs baseline: 1.2162x; 1.2066x over previous
//
#include <hip/hip_runtime.h>
#include <hip/hip_bf16.h>
#include <cstdint>
#include <cstdio>

typedef unsigned short u16;
typedef unsigned int   u32;
typedef __attribute__((ext_vector_type(8))) short bf16x8;   // 8 bf16 (4 VGPRs)
typedef __attribute__((ext_vector_type(4))) float f32x4;
typedef __attribute__((ext_vector_type(4))) u16   u16x4;
typedef __attribute__((ext_vector_type(8))) u16   u16x8;

#define GLOBAL_AS __attribute__((address_space(1)))
#define LDS_AS    __attribute__((address_space(3)))

static __device__ __forceinline__ u16 f2bf(float f) {
  u32 u = __builtin_bit_cast(u32, f);
  u = (u + 0x7fffu + ((u >> 16) & 1u)) >> 16;   // RNE
  return (u16)u;
}
static __device__ __forceinline__ float bf2f(u16 v) {
  return __builtin_bit_cast(float, (u32)v << 16);
}
static __device__ __forceinline__ void gload_lds16(const void* g, void* l) {
  __builtin_amdgcn_global_load_lds((GLOBAL_AS u32*)g, (LDS_AS u32*)l, 16, 0, 0);
}

// ---------------------------------------------------------------------------
__global__ void k_cvt(const float* __restrict__ src, int ld, int c0,
                      int rows_src, int cols4, int total4,
                      u16* __restrict__ dst, int ldd, int dcol) {
  int gid = blockIdx.x * 256 + threadIdx.x;
  if (gid >= total4) return;
  int r = gid / cols4;
  int c = (gid - r * cols4) * 4;
  u16x4 o = {0, 0, 0, 0};
  if (r < rows_src) {
    const float4 v = *(const float4*)&src[(size_t)r * ld + c0 + c];
    o[0] = f2bf(v.x); o[1] = f2bf(v.y); o[2] = f2bf(v.z); o[3] = f2bf(v.w);
  }
  *(u16x4*)&dst[(size_t)r * ldd + dcol + c] = o;
}

// ---------------------------------------------------------------------------
__global__ void k_init(const float* __restrict__ rough,
                       const float* __restrict__ bout,
                       float* __restrict__ out) {
  int i = blockIdx.x * 256 + threadIdx.x;
  if (i >= 1024 * 65) return;
  int bi = i / 65, c = i - bi * 65;
  out[i] = (c == 0) ? 1e-7f : rough[bi * 64 + c - 1] + bout[0];
}

// ---------------------------------------------------------------------------
// k_build_cmat: bf16 sources, 8 elems/thread. 136 = 1088/8 groups per row.
__global__ void k_build_cmat(const u16* __restrict__ A16,
                             const u16* __restrict__ allm16,
                             const float* __restrict__ pw,
                             const int* __restrict__ topidx,
                             u16* __restrict__ Cmat, int r0) {
  int gid = blockIdx.x * 256 + threadIdx.x;   // 16384*136 exact
  int lr = gid / 136;
  int c8 = gid - lr * 136;
  int r  = r0 + lr;
  u16x8 o;
  if (c8 < 128) {
    int k   = c8 * 8;
    int idx = topidx[r];
    int bi  = r >> 6;
    u16x8 a = *(const u16x8*)&A16[(size_t)bi * 1024 + k];
    u16x8 b = *(const u16x8*)&allm16[(size_t)idx * 1024 + k];
#pragma unroll
    for (int j = 0; j < 8; ++j) o[j] = f2bf(bf2f(a[j]) * bf2f(b[j]));
  } else {
    int k = (c8 - 128) * 8;
    float4 p0 = *(const float4*)&pw[(size_t)r * 64 + k];
    float4 p1 = *(const float4*)&pw[(size_t)r * 64 + k + 4];
    o[0] = f2bf(p0.x); o[1] = f2bf(p0.y); o[2] = f2bf(p0.z); o[3] = f2bf(p0.w);
    o[4] = f2bf(p1.x); o[5] = f2bf(p1.y); o[6] = f2bf(p1.z); o[7] = f2bf(p1.w);
  }
  *(u16x8*)&Cmat[(size_t)lr * 1088 + c8 * 8] = o;
}

// ---------------------------------------------------------------------------
// gemm128: 128x128 2-phase kernel, used only for the tiny Aproj GEMM.
// bias (b1) folded into the bf16 output.
__global__ __launch_bounds__(256)
void gemm128(const u16* __restrict__ A, int lda,
             const u16* __restrict__ B, int ldb, int Ksteps,
             u16* __restrict__ C, int ldc, const float* __restrict__ bias) {
  __shared__ u16 As[128 * 64];
  __shared__ u16 Bs[128 * 64];
  const int t = threadIdx.x;
  const int w = t >> 6, l = t & 63;
  const int wr = w >> 1, wc = w & 1;
  const int brow = blockIdx.x * 128;
  const int bcol = blockIdx.y * 128;
  const int srow = t >> 3;
  const int scol = (t & 7) * 8;
  const int gsw  = (((t & 7) ^ ((t >> 3) & 7))) * 8;

  f32x4 acc[4][4] = {};
  for (int ks = 0; ks < Ksteps; ++ks) {
    const int kb = ks * 64;
#pragma unroll
    for (int q = 0; q < 4; ++q) {
      int r = q * 32 + srow;
      gload_lds16(A + (size_t)(brow + r) * lda + kb + gsw, &As[r * 64 + scol]);
      gload_lds16(B + (size_t)(bcol + r) * ldb + kb + gsw, &Bs[r * 64 + scol]);
    }
    __syncthreads();
#pragma unroll
    for (int kk = 0; kk < 2; ++kk) {
      bf16x8 af[4], bfr[4];
      const int pg = ((kk * 4 + (l >> 4)) ^ (l & 7)) * 8;
#pragma unroll
      for (int m = 0; m < 4; ++m)
        af[m] = *(const bf16x8*)&As[(wr * 64 + m * 16 + (l & 15)) * 64 + pg];
#pragma unroll
      for (int n = 0; n < 4; ++n)
        bfr[n] = *(const bf16x8*)&Bs[(wc * 64 + n * 16 + (l & 15)) * 64 + pg];
#pragma unroll
      for (int m = 0; m < 4; ++m)
#pragma unroll
        for (int n = 0; n < 4; ++n)
          acc[m][n] = __builtin_amdgcn_mfma_f32_16x16x32_bf16(af[m], bfr[n], acc[m][n], 0, 0, 0);
    }
    __syncthreads();
  }
#pragma unroll
  for (int m = 0; m < 4; ++m)
#pragma unroll
    for (int n = 0; n < 4; ++n)
#pragma unroll
      for (int reg = 0; reg < 4; ++reg) {
        int row = brow + wr * 64 + m * 16 + (l >> 4) * 4 + reg;
        int col = bcol + wc * 64 + n * 16 + (l & 15);
        float v = acc[m][n][reg] + (bias ? bias[col] : 0.f);
        C[(size_t)row * ldc + col] = f2bf(v);
      }
}

// ---------------------------------------------------------------------------
// gemm256: 256x256, BK=64, 512 thr (8 waves 2Mx4N). r5-proven schedule:
// per phase: [ds_reads; stage ONE half-tile (2 gloads); (q0: lgkmcnt(8));
//   s_barrier; lgkmcnt(0); sched_barrier(0); setprio(1); 16 MFMA; setprio(0);
//   counted vmcnt (q0/q3 only); s_barrier]
// Stage placement: q0->Ah0(t+1), q1->Ah1(t+1), q2->Bh0(t+2), q3->Bh1(t+2).
// Ledger: q0-post vmcnt(6) guards Ah1(t); q3-post vmcnt(6) guards
//   B(t+1)+Ah0(t+1); tails 0/2. Prologue 6 stages; vmcnt(6).
// FUSED epilogue: Bproj 256-slice staged into LDS via gload_lds with the r7
//   verified XOR swizzle key=((row>>1)&7)<<3 src+read side (conflicts
//   524K -> 0, bit-identical output); Aproj(+b1) hoisted; leaky_relu; *Wout;
//   16-lane shfl reduce; atomicAdd.
template<bool FUSED>
__global__ __launch_bounds__(512, 1)
void gemm256(const u16* __restrict__ A, int lda,
             const u16* __restrict__ B, int ldb, int NT,
             u16* __restrict__ C, int ldc,
             const u16* __restrict__ Aproj, const u16* __restrict__ Bproj,
             const float* __restrict__ Wout,
             const int* __restrict__ topidx, float* __restrict__ out, int r0) {
  extern __shared__ u16 lds[];
  u16* As = lds;                        // [2buf][2half][128][64], rows bit5-interleaved
  u16* Bs = lds + 2 * 2 * 128 * 64;     // [2buf][256][64]

  const int t = threadIdx.x;
  const int l = t & 63;
  const int w = t >> 6;                 // 0..7
  const int wrow = w >> 2, wcol = w & 3;
  const int brow = blockIdx.x * 256;
  const int bcol = blockIdx.y * 256;

  const int sr  = t >> 3;               // 0..63
  const int sc  = (t & 7) * 8;          // linear LDS dest col
  const int gsw = ((t & 7) ^ (sr & 7)) * 8;  // pre-swizzled source col

  auto stageA = [&](int kt, int h) {    // one A half-tile: 2 loads
    if (kt >= NT) return;
#pragma unroll
    for (int s = 0; s < 2; ++s) {
      int lr = sr + 64 * s;
      int g  = ((lr >> 5) << 6) + h * 32 + (lr & 31);   // bit5-interleave
      gload_lds16(A + (size_t)(brow + g) * lda + kt * 64 + gsw,
                  &As[(((kt & 1) * 2 + h) * 128 + lr) * 64 + sc]);
    }
  };
  auto stageB = [&](int kt, int h) {    // one B half-tile: 2 loads
    if (kt >= NT) return;
#pragma unroll
    for (int s = 0; s < 2; ++s) {
      int lr = h * 128 + sr + 64 * s;
      gload_lds16(B + (size_t)(bcol + lr) * ldb + kt * 64 + gsw,
                  &Bs[((kt & 1) * 256 + lr) * 64 + sc]);
    }
  };

  f32x4 acc[8][4] = {};

  // prologue: steady-state issue order
  stageB(0, 0); stageB(0, 1); stageA(0, 0); stageA(0, 1);
  stageB(1, 0); stageB(1, 1);
  asm volatile("s_waitcnt vmcnt(6)" ::: "memory");   // B(0)+Ah0(0) landed
  __builtin_amdgcn_s_barrier();

  for (int kt = 0; kt < NT; ++kt) {
    const int cbuf = kt & 1;
    bf16x8 bfr[4][2];                   // B frags, live all 4 phases
#pragma unroll
    for (int q = 0; q < 4; ++q) {
      // --- ds reads (pre-barrier) ---
      if (q == 0) {
#pragma unroll
        for (int n = 0; n < 4; ++n) {
          int row = wcol * 64 + n * 16 + (l & 15);
#pragma unroll
          for (int kk = 0; kk < 2; ++kk) {
            int gran = (kk * 4 + (l >> 4)) ^ (l & 7);
            bfr[n][kk] = *(const bf16x8*)&Bs[(cbuf * 256 + row) * 64 + gran * 8];
          }
        }
      }
      bf16x8 af[2][2];
#pragma unroll
      for (int m2 = 0; m2 < 2; ++m2) {
        int m = 2 * q + m2;
        int g = wrow * 128 + m * 16 + (l & 15);
        int lra = ((g >> 6) << 5) + (g & 31);
#pragma unroll
        for (int kk = 0; kk < 2; ++kk) {
          int gran = (kk * 4 + (l >> 4)) ^ (l & 7);
          af[m2][kk] = *(const bf16x8*)&As[((cbuf * 2 + (q & 1)) * 128 + lra) * 64 + gran * 8];
        }
      }

      // --- stage exactly one half-tile ---
      if      (q == 0) stageA(kt + 1, 0);
      else if (q == 1) stageA(kt + 1, 1);
      else if (q == 2) stageB(kt + 2, 0);
      else             stageB(kt + 2, 1);

      if (q == 0) asm volatile("s_waitcnt lgkmcnt(8)" ::: "memory");
      __builtin_amdgcn_s_barrier();
      asm volatile("s_waitcnt lgkmcnt(0)" ::: "memory");
      __builtin_amdgcn_sched_barrier(0);
      __builtin_amdgcn_s_setprio(1);
#pragma unroll
      for (int m2 = 0; m2 < 2; ++m2)
#pragma unroll
        for (int n = 0; n < 4; ++n)
#pragma unroll
          for (int kk = 0; kk < 2; ++kk)
            acc[2 * q + m2][n] = __builtin_amdgcn_mfma_f32_16x16x32_bf16(
                af[m2][kk], bfr[n][kk], acc[2 * q + m2][n], 0, 0, 0);
      __builtin_amdgcn_s_setprio(0);

      // --- counted waits (q0/q3 only), then closing barrier ---
      if (q == 0) {
        if (kt + 1 < NT) asm volatile("s_waitcnt vmcnt(6)" ::: "memory");
        else             asm volatile("s_waitcnt vmcnt(0)" ::: "memory");
      } else if (q == 3 && kt + 1 < NT) {
        if (kt + 2 < NT) asm volatile("s_waitcnt vmcnt(6)" ::: "memory");
        else             asm volatile("s_waitcnt vmcnt(2)" ::: "memory");
      }
      __builtin_amdgcn_s_barrier();
    }
  }

  // --- epilogue ---
  if constexpr (FUSED) {
    __syncthreads();
    u16* Pb = lds;                      // [256][256], r7-verified XOR swizzle
#pragma unroll
    for (int pass = 0; pass < 16; ++pass) {
      int rr = pass * 16 + (t >> 5);
      int mi = topidx[r0 + brow + rr];
      int cc = (t & 31) * 8;
      int scc = cc ^ (((rr >> 1) & 7) << 3);   // src-side swizzle
      gload_lds16(&Bproj[(size_t)mi * 1024 + bcol + scc], &Pb[rr * 256 + cc]);
    }
    asm volatile("s_waitcnt vmcnt(0)" ::: "memory");
    __syncthreads();

    float wo[4], av[2][4];
    const int bi0 = ((r0 + brow) >> 6) + wrow * 2;
#pragma unroll
    for (int n = 0; n < 4; ++n) {
      int col = bcol + wcol * 64 + n * 16 + (l & 15);
      wo[n] = Wout[col];
#pragma unroll
      for (int j = 0; j < 2; ++j)
        av[j][n] = bf2f(Aproj[(size_t)(bi0 + j) * 1024 + col]);   // b1 pre-folded
    }
#pragma unroll
    for (int m = 0; m < 8; ++m) {
#pragma unroll
      for (int reg = 0; reg < 4; ++reg) {
        int lrow = wrow * 128 + m * 16 + (l >> 4) * 4 + reg;
        int gr = r0 + brow + lrow;
        int key = ((lrow >> 1) & 7) << 3;      // read-side swizzle (same involution)
        float s = 0.f;
#pragma unroll
        for (int n = 0; n < 4; ++n) {
          int lcol = wcol * 64 + n * 16 + (l & 15);
          float v = acc[m][n][reg] + av[m >> 2][n] + bf2f(Pb[lrow * 256 + (lcol ^ key)]);
          v = v > 0.f ? v : 0.01f * v;          // leaky_relu(0.01)
          s += v * wo[n];
        }
        s += __shfl_xor(s, 1);
        s += __shfl_xor(s, 2);
        s += __shfl_xor(s, 4);
        s += __shfl_xor(s, 8);
        if ((l & 15) == 0)
          atomicAdd(&out[(gr >> 6) * 65 + 1 + (gr & 63)], s);
      }
    }
  } else {
#pragma unroll
    for (int m = 0; m < 8; ++m)
#pragma unroll
      for (int n = 0; n < 4; ++n)
#pragma unroll
        for (int reg = 0; reg < 4; ++reg) {
          int row = brow + wrow * 128 + m * 16 + (l >> 4) * 4 + reg;
          int col = bcol + wcol * 64 + n * 16 + (l & 15);
          C[(size_t)row * ldc + col] = f2bf(acc[m][n][reg]);
        }
  }
}

// ---------------------------------------------------------------------------
extern "C" void kernel_launch(void* const* d_in, const int* in_sizes, int n_in,
                              void* d_out, int out_size, void* d_ws, size_t ws_size,
                              hipStream_t stream) {
  const float* allm  = (const float*)d_in[0];   // [10000,1024]
  const float* ments = (const float*)d_in[1];   // [1024,1024]
  const float* pw    = (const float*)d_in[2];   // [1024,64,64]
  const int*   tidx  = (const int*)d_in[3];     // [1024,64]
  const float* rough = (const float*)d_in[4];   // [1024,64]
  const float* W1    = (const float*)d_in[5];   // [1024,3136]
  const float* b1    = (const float*)d_in[6];   // [1024]
  const float* Wout  = (const float*)d_in[7];   // [1,1024]
  const float* bout  = (const float*)d_in[8];   // [1]
  float* out = (float*)d_out;                   // [1024,65]

  const int CHUNK = 16384;
  u16* A16    = (u16*)d_ws;                 // 1024*1024 (ments bf16)
  u16* allm16 = A16 + 1024 * 1024;          // 10240*1024 (rows>=10000 zero)
  u16* W1a    = allm16 + 10240 * 1024;      // 1024*1024
  u16* W1b    = W1a + 1024 * 1024;          // 1024*1024
  u16* W1cp   = W1b + 1024 * 1024;          // 1024*1088
  u16* Aproj  = W1cp + 1024 * 1088;         // 1024*1024 bf16 (holds Aproj+b1)
  u16* Bproj  = Aproj + 1024 * 1024;        // 10240*1024 bf16
  u16* Cmat   = Bproj + 10240 * 1024;       // CHUNK*1088 bf16

  size_t need = (size_t)2 * ((size_t)1024*1024 + 10240*1024 + 1024*1024 + 1024*1024
              + 1024*1088 + 1024*1024 + 10240*1024 + (size_t)CHUNK*1088);
  if (ws_size < need) {
    fprintf(stderr, "kernel_launch: ws_size %zu < needed %zu\n", ws_size, need);
    return;
  }

  hipFuncSetAttribute((const void*)&gemm256<false>,
                      hipFuncAttributeMaxDynamicSharedMemorySize, 131072);
  hipFuncSetAttribute((const void*)&gemm256<true>,
                      hipFuncAttributeMaxDynamicSharedMemorySize, 131072);

  // --- conversions / weight splits (bf16) ---
  {
    int t4;
    t4 = 1024 * 256;
    k_cvt<<<(t4 + 255) / 256, 256, 0, stream>>>(W1, 3136, 0,    1024, 256, t4, W1a, 1024, 0);
    k_cvt<<<(t4 + 255) / 256, 256, 0, stream>>>(W1, 3136, 1024, 1024, 256, t4, W1b, 1024, 0);
    k_cvt<<<(t4 + 255) / 256, 256, 0, stream>>>(W1, 3136, 2048, 1024, 256, t4, W1cp, 1088, 0);
    t4 = 1024 * 16;
    k_cvt<<<(t4 + 255) / 256, 256, 0, stream>>>(W1, 3136, 3072, 1024, 16, t4, W1cp, 1088, 1024);
    t4 = 1024 * 256;
    k_cvt<<<(t4 + 255) / 256, 256, 0, stream>>>(ments, 1024, 0, 1024, 256, t4, A16, 1024, 0);
    t4 = 10240 * 256;
    k_cvt<<<(t4 + 255) / 256, 256, 0, stream>>>(allm, 1024, 0, 10000, 256, t4, allm16, 1024, 0);
  }

  // --- projection GEMMs (Aproj gets +b1 folded) ---
  gemm128<<<dim3(8, 8), 256, 0, stream>>>(A16, 1024, W1a, 1024, 16, Aproj, 1024, b1);
  gemm256<false><<<dim3(40, 4), 512, 131072, stream>>>(allm16, 1024, W1b, 1024, 16,
                                                       Bproj, 1024,
                                                       nullptr, nullptr, nullptr,
                                                       nullptr, nullptr, 0);

  // --- init out with EPS column and rough+bout ---
  k_init<<<260, 256, 0, stream>>>(rough, bout, out);

  // --- chunked: build Cmat = [a*b | pw] bf16, then fused 256^2 GEMM+epilogue ---
  for (int c = 0; c < 4; ++c) {
    int r0 = c * CHUNK;
    k_build_cmat<<<(CHUNK * 136) / 256, 256, 0, stream>>>(A16, allm16, pw, tidx, Cmat, r0);
    gemm256<true><<<dim3(CHUNK / 256, 4), 512, 131072, stream>>>(Cmat, 1088, W1cp, 1088, 17,
                                                                 nullptr, 0,
                                                                 Aproj, Bproj, Wout,
                                                                 tidx, out, r0);
  }
}